// Round 14
// baseline (946.677 us; speedup 1.0000x reference)
//
#include <hip/hip_runtime.h>
#include <hip/hip_bf16.h>
#include <cstdint>

#define B_ 256
#define T_ 512
#define F_ 128
#define H_ 128
#define G3_ 384
#define R_ 8
#define K_ 64

typedef __attribute__((ext_vector_type(8))) short short8_t;
typedef __attribute__((ext_vector_type(4))) float f32x4;
typedef __attribute__((ext_vector_type(2))) float f32x2;
typedef __attribute__((ext_vector_type(4))) unsigned int u32x4;
typedef __attribute__((ext_vector_type(4))) unsigned short u16x4;

__device__ __forceinline__ float sigm(float x) { return 1.f / (1.f + __expf(-x)); }
__device__ __forceinline__ float tanh_f(float x) { return 1.f - 2.f / (1.f + __expf(2.f * x)); }
__device__ __forceinline__ unsigned short f2bf(float f) {
    uint32_t u = __builtin_bit_cast(uint32_t, f);
    return (unsigned short)((u + 0x7FFFu + ((u >> 16) & 1u)) >> 16);
}
__device__ __forceinline__ float bf2f(unsigned short u) {
    return __builtin_bit_cast(float, (uint32_t)u << 16);
}
__device__ __forceinline__ short8_t pack8(float4 a, float4 b) {
    short8_t v;
    v[0] = (short)f2bf(a.x); v[1] = (short)f2bf(a.y);
    v[2] = (short)f2bf(a.z); v[3] = (short)f2bf(a.w);
    v[4] = (short)f2bf(b.x); v[5] = (short)f2bf(b.y);
    v[6] = (short)f2bf(b.z); v[7] = (short)f2bf(b.w);
    return v;
}

// Quad-local butterfly adds on the VALU pipe (DPP quad_perm).
__device__ __forceinline__ float dpp_red2(float x) {
    int a = __builtin_amdgcn_mov_dpp(__builtin_bit_cast(int, x), 0xB1, 0xF, 0xF, true);
    x += __builtin_bit_cast(float, a);
    int b = __builtin_amdgcn_mov_dpp(__builtin_bit_cast(int, x), 0x4E, 0xF, 0xF, true);
    x += __builtin_bit_cast(float, b);
    return x;
}

// MFMA GEMM: C[m][n] = sum_k A[m][k]*W[n][k] + bias[n]; C is BF16 now
// (write volume halved: 201->100MB). A is fp32 (layer 1: x) or bf16
// (layer 2: h1) via template. D restaged through a bf16 LDS strip
// ([16][392] ushort, 16B-aligned rows) -> contiguous dwordx4 stores.
template<bool ABF16>
__global__ __launch_bounds__(512, 2) void gemm_gi_mfma(const void* __restrict__ Av,
                                                       const float* __restrict__ W,
                                                       const float* __restrict__ bias,
                                                       unsigned short* __restrict__ C)
{
    __shared__ alignas(16) unsigned short A_lds[128 * 128];   // bf16, swizzled
    __shared__ alignas(16) unsigned short D_lds[16 * 392];    // bf16 strip

    const int tid = threadIdx.x;
    const int wv = tid >> 6, lane = tid & 63;
    const int lc = lane & 15, lg = lane >> 4;
    const size_t m0 = (size_t)blockIdx.x * 128;

    short8_t bf[3][4];
    float bi[3];
    #pragma unroll
    for (int u = 0; u < 3; ++u) {
        const int n = 48 * wv + 16 * u + lc;
        bi[u] = bias[n];
        #pragma unroll
        for (int ks = 0; ks < 4; ++ks) {
            const float4* wp = (const float4*)(W + (size_t)n * 128 + ks * 32 + lg * 8);
            bf[u][ks] = pack8(wp[0], wp[1]);
        }
    }

    {
        const int m = tid >> 2, kq = tid & 3;
        char* base = (char*)A_lds;
        const int bb = m * 256 + kq * 64, sw = (m & 7) << 4;
        if constexpr (ABF16) {
            const short8_t* ap = (const short8_t*)((const unsigned short*)Av + (m0 + m) * 128 + kq * 32);
            short8_t v0 = ap[0], v1 = ap[1], v2 = ap[2], v3 = ap[3];
            *(short8_t*)(base + ((bb +  0) ^ sw)) = v0;
            *(short8_t*)(base + ((bb + 16) ^ sw)) = v1;
            *(short8_t*)(base + ((bb + 32) ^ sw)) = v2;
            *(short8_t*)(base + ((bb + 48) ^ sw)) = v3;
        } else {
            const float4* ap = (const float4*)((const float*)Av + (m0 + m) * 128 + kq * 32);
            float4 v0 = ap[0], v1 = ap[1], v2 = ap[2], v3 = ap[3];
            float4 v4 = ap[4], v5 = ap[5], v6 = ap[6], v7 = ap[7];
            *(short8_t*)(base + ((bb +  0) ^ sw)) = pack8(v0, v1);
            *(short8_t*)(base + ((bb + 16) ^ sw)) = pack8(v2, v3);
            *(short8_t*)(base + ((bb + 32) ^ sw)) = pack8(v4, v5);
            *(short8_t*)(base + ((bb + 48) ^ sw)) = pack8(v6, v7);
        }
    }
    __syncthreads();

    const char* Ab = (const char*)A_lds;
    for (int mt = 0; mt < 8; ++mt) {
        short8_t af0 = *(const short8_t*)(Ab + (((mt * 16 + lc) * 256 +  0 + lg * 16) ^ ((lc & 7) << 4)));
        short8_t af1 = *(const short8_t*)(Ab + (((mt * 16 + lc) * 256 + 64 + lg * 16) ^ ((lc & 7) << 4)));
        short8_t af2 = *(const short8_t*)(Ab + (((mt * 16 + lc) * 256 + 128 + lg * 16) ^ ((lc & 7) << 4)));
        short8_t af3 = *(const short8_t*)(Ab + (((mt * 16 + lc) * 256 + 192 + lg * 16) ^ ((lc & 7) << 4)));
        f32x4 a0 = {0.f, 0.f, 0.f, 0.f}, a1 = a0, a2 = a0;
        a0 = __builtin_amdgcn_mfma_f32_16x16x32_bf16(af0, bf[0][0], a0, 0, 0, 0);
        a1 = __builtin_amdgcn_mfma_f32_16x16x32_bf16(af0, bf[1][0], a1, 0, 0, 0);
        a2 = __builtin_amdgcn_mfma_f32_16x16x32_bf16(af0, bf[2][0], a2, 0, 0, 0);
        a0 = __builtin_amdgcn_mfma_f32_16x16x32_bf16(af1, bf[0][1], a0, 0, 0, 0);
        a1 = __builtin_amdgcn_mfma_f32_16x16x32_bf16(af1, bf[1][1], a1, 0, 0, 0);
        a2 = __builtin_amdgcn_mfma_f32_16x16x32_bf16(af1, bf[2][1], a2, 0, 0, 0);
        a0 = __builtin_amdgcn_mfma_f32_16x16x32_bf16(af2, bf[0][2], a0, 0, 0, 0);
        a1 = __builtin_amdgcn_mfma_f32_16x16x32_bf16(af2, bf[1][2], a1, 0, 0, 0);
        a2 = __builtin_amdgcn_mfma_f32_16x16x32_bf16(af2, bf[2][2], a2, 0, 0, 0);
        a0 = __builtin_amdgcn_mfma_f32_16x16x32_bf16(af3, bf[0][3], a0, 0, 0, 0);
        a1 = __builtin_amdgcn_mfma_f32_16x16x32_bf16(af3, bf[1][3], a1, 0, 0, 0);
        a2 = __builtin_amdgcn_mfma_f32_16x16x32_bf16(af3, bf[2][3], a2, 0, 0, 0);

        // ---- restage D strip (bf16): regs -> LDS
        asm volatile("s_waitcnt lgkmcnt(0)" ::: "memory");
        __builtin_amdgcn_s_barrier();
        #pragma unroll
        for (int r = 0; r < 4; ++r) {
            unsigned short* dp = D_lds + (4 * lg + r) * 392 + 48 * wv + lc;
            dp[0]  = f2bf(a0[r] + bi[0]);
            dp[16] = f2bf(a1[r] + bi[1]);
            dp[32] = f2bf(a2[r] + bi[2]);
        }
        asm volatile("s_waitcnt lgkmcnt(0)" ::: "memory");
        __builtin_amdgcn_s_barrier();

        // ---- LDS -> global: strip rows are 384 ushort (48 x 16B units),
        // LDS row stride 392 ushort (49 units) -> src unit = idx + idx/48.
        unsigned short* cbase = C + (m0 + mt * 16) * G3_;
        u32x4* cg = (u32x4*)cbase;
        #pragma unroll
        for (int i = 0; i < 2; ++i) {
            int idx = tid + 512 * i;
            if (idx < 768) {
                const u32x4* src = (const u32x4*)(D_lds + (size_t)idx * 8 + (idx / 48) * 8);
                cg[idx] = *src;                 // fire-and-forget
            }
        }
    }
}

// r9-exact recurrence structure; gi/hout are now BF16 (recurrence math and
// LDS h stay fp32; prefetch registers hold raw u16 so vmcnt still hides).
__global__ __launch_bounds__(512, 2) void gru_seq(const unsigned short* __restrict__ gi,
                                                  const float* __restrict__ Whh,
                                                  const float* __restrict__ bhh,
                                                  unsigned short* __restrict__ hout)
{
    __shared__ alignas(16) float hbuf[2][4][36];

    const int tid = threadIdx.x;
    const int b = blockIdx.x;
    const int w = tid >> 6, lane = tid & 63;
    const int j = 16 * w + (lane >> 2);
    const int s = lane & 3;
    const bool fin = (s == 0);

    f32x2 wr2[16], wz2[16], wn2[16];
    {
        const float4* p0 = (const float4*)(Whh + (size_t)j * 128 + s * 32);
        const float4* p1 = (const float4*)(Whh + (size_t)(128 + j) * 128 + s * 32);
        const float4* p2 = (const float4*)(Whh + (size_t)(256 + j) * 128 + s * 32);
        #pragma unroll
        for (int q = 0; q < 8; ++q) {
            float4 v0 = p0[q], v1 = p1[q], v2 = p2[q];
            wr2[2*q]   = f32x2{v0.x, v0.y};
            wr2[2*q+1] = f32x2{v0.z, v0.w};
            wz2[2*q]   = f32x2{v1.x, v1.y};
            wz2[2*q+1] = f32x2{v1.z, v1.w};
            wn2[2*q]   = f32x2{v2.x, v2.y};
            wn2[2*q+1] = f32x2{v2.z, v2.w};
        }
    }
    const float br = bhh[j], bz = bhh[128 + j], bn = bhh[256 + j];

    if (tid < H_) hbuf[0][tid >> 5][tid & 31] = 0.f;
    __syncthreads();

    const unsigned short* gip = gi + (size_t)b * T_ * G3_ + j;
    unsigned short* hop = hout + (size_t)b * T_ * H_ + j;

    unsigned short g0[3], g1[3], g2[3], g3[3];
    if (fin) {
        #pragma unroll
        for (int u = 0; u < 3; ++u) {
            g0[u] = gip[0 * G3_ + 128 * u];
            g1[u] = gip[1 * G3_ + 128 * u];
            g2[u] = gip[2 * G3_ + 128 * u];
            g3[u] = gip[3 * G3_ + 128 * u];
        }
    }
    float hprev = 0.f;

    auto step = [&](int t, unsigned short (&gc)[3]) {
        const int p = t & 1;
        const float4* hv = (const float4*)(&hbuf[p][s][0]);
        f32x2 pr2 = {0.f, 0.f}, pz2 = pr2, pn2 = pr2;
        #pragma unroll
        for (int q = 0; q < 8; ++q) {
            float4 h4 = hv[q];
            f32x2 ha = {h4.x, h4.y};
            f32x2 hb = {h4.z, h4.w};
            pr2 += wr2[2*q] * ha;  pr2 += wr2[2*q+1] * hb;
            pz2 += wz2[2*q] * ha;  pz2 += wz2[2*q+1] * hb;
            pn2 += wn2[2*q] * ha;  pn2 += wn2[2*q+1] * hb;
        }
        float pr = dpp_red2(pr2[0] + pr2[1]);
        float pz = dpp_red2(pz2[0] + pz2[1]);
        float pn = dpp_red2(pn2[0] + pn2[1]);

        if (fin) {
            float r  = sigm(bf2f(gc[0]) + pr + br);
            float z  = sigm(bf2f(gc[1]) + pz + bz);
            float nn = tanh_f(bf2f(gc[2]) + r * (pn + bn));
            float h  = (1.f - z) * nn + z * hprev;
            hprev = h;
            hbuf[p ^ 1][j >> 5][j & 31] = h;
            hop[(size_t)t * H_] = f2bf(h);               // fire-and-forget
            int tn = (t + 4 < T_) ? t + 4 : T_ - 1;
            const unsigned short* gp = gip + (size_t)tn * G3_;
            gc[0] = gp[0]; gc[1] = gp[128]; gc[2] = gp[256];
        }
        asm volatile("s_waitcnt lgkmcnt(0)" ::: "memory");
        __builtin_amdgcn_s_barrier();
    };

    for (int t = 0; t < T_; t += 4) {
        step(t + 0, g0);
        step(t + 1, g1);
        step(t + 2, g2);
        step(t + 3, g3);
    }
}

// One wave per sample; h2 is bf16 now (staged to fp32 in LDS).
__global__ __launch_bounds__(256) void head_k(const unsigned short* __restrict__ h2,
                                              const float* __restrict__ x,
                                              const int* __restrict__ regime,
                                              const float* __restrict__ W1,
                                              const float* __restrict__ b1,
                                              const float* __restrict__ W2,
                                              const float* __restrict__ b2,
                                              const float* __restrict__ lag_scale,
                                              const float* __restrict__ lag_bias,
                                              float* __restrict__ out)
{
    __shared__ alignas(16) float hrow[4][128];
    const int tid = threadIdx.x;
    const int wv = tid >> 6, lane = tid & 63;
    const size_t s = (size_t)blockIdx.x * 4 + wv;
    const int reg = regime[s];

    if (lane < 32) {
        u16x4 hv4 = *(const u16x4*)(h2 + s * H_ + 4 * lane);
        float4 f;
        f.x = bf2f(hv4[0]); f.y = bf2f(hv4[1]);
        f.z = bf2f(hv4[2]); f.w = bf2f(hv4[3]);
        *(float4*)&hrow[wv][4 * lane] = f;
    }
    __syncthreads();

    float acc = b1[reg * K_ + lane];
    const float* Wp = W1 + (size_t)reg * H_ * K_ + lane;
    const float4* h4p = (const float4*)hrow[wv];
    #pragma unroll
    for (int q = 0; q < 32; ++q) {
        float4 h4 = h4p[q];
        acc += h4.x * Wp[(4 * q + 0) * K_];
        acc += h4.y * Wp[(4 * q + 1) * K_];
        acc += h4.z * Wp[(4 * q + 2) * K_];
        acc += h4.w * Wp[(4 * q + 3) * K_];
    }
    float silu = acc * sigm(acc);
    float v = silu * W2[reg * K_ + lane];
    #pragma unroll
    for (int m = 1; m < 64; m <<= 1) v += __shfl_xor(v, m);
    if (lane == 0) {
        float lag = lag_scale[0] * x[s * F_] + lag_bias[0];
        out[s] = lag + v + b2[reg];
    }
}

extern "C" void kernel_launch(void* const* d_in, const int* in_sizes, int n_in,
                              void* d_out, int out_size, void* d_ws, size_t ws_size,
                              hipStream_t stream) {
    const float* x         = (const float*)d_in[0];
    const int*   regime    = (const int*)d_in[1];
    const float* lag_scale = (const float*)d_in[2];
    const float* lag_bias  = (const float*)d_in[3];
    const float* Wih0      = (const float*)d_in[4];
    const float* Whh0      = (const float*)d_in[5];
    const float* bih0      = (const float*)d_in[6];
    const float* bhh0      = (const float*)d_in[7];
    const float* Wih1      = (const float*)d_in[8];
    const float* Whh1      = (const float*)d_in[9];
    const float* bih1      = (const float*)d_in[10];
    const float* bhh1      = (const float*)d_in[11];
    const float* W1        = (const float*)d_in[12];
    const float* b1        = (const float*)d_in[13];
    const float* W2        = (const float*)d_in[14];
    const float* b2        = (const float*)d_in[15];
    float* out = (float*)d_out;

    const size_t NT = (size_t)B_ * T_;                       // 131072
    const size_t need = NT * G3_ * 2 + NT * H_ * 2;          // 134 MiB (bf16)
    if (ws_size < need) {
        hipMemsetAsync(d_out, 0x7F, (size_t)out_size * 4, stream);
        return;
    }
    unsigned short* gi = (unsigned short*)d_ws;              // bf16 gates
    unsigned short* hb = gi + NT * G3_;                      // bf16 h

    const int gblocks = (int)(NT / 128);                     // 1024
    gemm_gi_mfma<false><<<gblocks, 512, 0, stream>>>((const void*)x, Wih0, bih0, gi);
    gru_seq<<<B_, 512, 0, stream>>>(gi, Whh0, bhh0, hb);
    gemm_gi_mfma<true><<<gblocks, 512, 0, stream>>>((const void*)hb, Wih1, bih1, gi);
    gru_seq<<<B_, 512, 0, stream>>>(gi, Whh1, bhh1, hb);
    head_k<<<(int)(NT / 4), 256, 0, stream>>>(hb, x, regime, W1, b1, W2, b2,
                                              lag_scale, lag_bias, out);
}

// Round 15
// 875.585 us; speedup vs baseline: 1.0812x; 1.0812x over previous
//
#include <hip/hip_runtime.h>
#include <hip/hip_bf16.h>
#include <cstdint>

#define B_ 256
#define T_ 512
#define F_ 128
#define H_ 128
#define G3_ 384
#define R_ 8
#define K_ 64

typedef __attribute__((ext_vector_type(8))) short short8_t;
typedef __attribute__((ext_vector_type(4))) float f32x4;
typedef __attribute__((ext_vector_type(2))) float f32x2;
typedef __attribute__((ext_vector_type(4))) unsigned int u32x4;
typedef __attribute__((ext_vector_type(2))) unsigned int u32x2;

__device__ __forceinline__ float sigm(float x) { return 1.f / (1.f + __expf(-x)); }
__device__ __forceinline__ float tanh_f(float x) { return 1.f - 2.f / (1.f + __expf(2.f * x)); }
__device__ __forceinline__ unsigned short f2bf(float f) {
    uint32_t u = __builtin_bit_cast(uint32_t, f);
    return (unsigned short)((u + 0x7FFFu + ((u >> 16) & 1u)) >> 16);
}
__device__ __forceinline__ short8_t pack8(float4 a, float4 b) {
    short8_t v;
    v[0] = (short)f2bf(a.x); v[1] = (short)f2bf(a.y);
    v[2] = (short)f2bf(a.z); v[3] = (short)f2bf(a.w);
    v[4] = (short)f2bf(b.x); v[5] = (short)f2bf(b.y);
    v[6] = (short)f2bf(b.z); v[7] = (short)f2bf(b.w);
    return v;
}

// Quad-local butterfly adds on the VALU pipe (DPP quad_perm).
__device__ __forceinline__ float dpp_red2(float x) {
    int a = __builtin_amdgcn_mov_dpp(__builtin_bit_cast(int, x), 0xB1, 0xF, 0xF, true);
    x += __builtin_bit_cast(float, a);
    int b = __builtin_amdgcn_mov_dpp(__builtin_bit_cast(int, x), 0x4E, 0xF, 0xF, true);
    x += __builtin_bit_cast(float, b);
    return x;
}

// MFMA GEMM producing GATE-INTERLEAVED bf16 gi: C[m][j][g], g in {r,z,n,pad},
// row = 512 ushort (1KB). A fp32. D restaged through LDS strip [16][520]
// (interleave applied at restage); copy-out is contiguous dwordx4 stores.
__global__ __launch_bounds__(512, 2) void gemm_gi_mfma(const float* __restrict__ A,
                                                       const float* __restrict__ W,
                                                       const float* __restrict__ bias,
                                                       unsigned short* __restrict__ C)
{
    __shared__ alignas(16) unsigned short A_lds[128 * 128];   // bf16, swizzled
    __shared__ alignas(16) unsigned short D_lds[16 * 520];    // interleaved strip

    const int tid = threadIdx.x;
    const int wv = tid >> 6, lane = tid & 63;
    const int lc = lane & 15, lg = lane >> 4;
    const size_t m0 = (size_t)blockIdx.x * 128;

    short8_t bf[3][4];
    float bi[3];
    int col[3];          // interleaved column j*4+g for each u
    bool zpad[3];        // this (wv,u) also zeroes the pad slot (g==0 owners)
    #pragma unroll
    for (int u = 0; u < 3; ++u) {
        const int n = 48 * wv + 16 * u + lc;
        const int g = n >> 7, j = n & 127;
        col[u] = j * 4 + g;
        zpad[u] = (g == 0);
        bi[u] = bias[n];
        #pragma unroll
        for (int ks = 0; ks < 4; ++ks) {
            const float4* wp = (const float4*)(W + (size_t)n * 128 + ks * 32 + lg * 8);
            bf[u][ks] = pack8(wp[0], wp[1]);
        }
    }

    {
        const int m = tid >> 2, kq = tid & 3;
        const float4* ap = (const float4*)(A + (m0 + m) * 128 + kq * 32);
        float4 v0 = ap[0], v1 = ap[1], v2 = ap[2], v3 = ap[3];
        float4 v4 = ap[4], v5 = ap[5], v6 = ap[6], v7 = ap[7];
        char* base = (char*)A_lds;
        const int bb = m * 256 + kq * 64, sw = (m & 7) << 4;
        *(short8_t*)(base + ((bb +  0) ^ sw)) = pack8(v0, v1);
        *(short8_t*)(base + ((bb + 16) ^ sw)) = pack8(v2, v3);
        *(short8_t*)(base + ((bb + 32) ^ sw)) = pack8(v4, v5);
        *(short8_t*)(base + ((bb + 48) ^ sw)) = pack8(v6, v7);
    }
    __syncthreads();

    const char* Ab = (const char*)A_lds;
    for (int mt = 0; mt < 8; ++mt) {
        short8_t af0 = *(const short8_t*)(Ab + (((mt * 16 + lc) * 256 +  0 + lg * 16) ^ ((lc & 7) << 4)));
        short8_t af1 = *(const short8_t*)(Ab + (((mt * 16 + lc) * 256 + 64 + lg * 16) ^ ((lc & 7) << 4)));
        short8_t af2 = *(const short8_t*)(Ab + (((mt * 16 + lc) * 256 + 128 + lg * 16) ^ ((lc & 7) << 4)));
        short8_t af3 = *(const short8_t*)(Ab + (((mt * 16 + lc) * 256 + 192 + lg * 16) ^ ((lc & 7) << 4)));
        f32x4 a0 = {0.f, 0.f, 0.f, 0.f}, a1 = a0, a2 = a0;
        a0 = __builtin_amdgcn_mfma_f32_16x16x32_bf16(af0, bf[0][0], a0, 0, 0, 0);
        a1 = __builtin_amdgcn_mfma_f32_16x16x32_bf16(af0, bf[1][0], a1, 0, 0, 0);
        a2 = __builtin_amdgcn_mfma_f32_16x16x32_bf16(af0, bf[2][0], a2, 0, 0, 0);
        a0 = __builtin_amdgcn_mfma_f32_16x16x32_bf16(af1, bf[0][1], a0, 0, 0, 0);
        a1 = __builtin_amdgcn_mfma_f32_16x16x32_bf16(af1, bf[1][1], a1, 0, 0, 0);
        a2 = __builtin_amdgcn_mfma_f32_16x16x32_bf16(af1, bf[2][1], a2, 0, 0, 0);
        a0 = __builtin_amdgcn_mfma_f32_16x16x32_bf16(af2, bf[0][2], a0, 0, 0, 0);
        a1 = __builtin_amdgcn_mfma_f32_16x16x32_bf16(af2, bf[1][2], a1, 0, 0, 0);
        a2 = __builtin_amdgcn_mfma_f32_16x16x32_bf16(af2, bf[2][2], a2, 0, 0, 0);
        a0 = __builtin_amdgcn_mfma_f32_16x16x32_bf16(af3, bf[0][3], a0, 0, 0, 0);
        a1 = __builtin_amdgcn_mfma_f32_16x16x32_bf16(af3, bf[1][3], a1, 0, 0, 0);
        a2 = __builtin_amdgcn_mfma_f32_16x16x32_bf16(af3, bf[2][3], a2, 0, 0, 0);

        asm volatile("s_waitcnt lgkmcnt(0)" ::: "memory");
        __builtin_amdgcn_s_barrier();
        #pragma unroll
        for (int r = 0; r < 4; ++r) {
            unsigned short* row = D_lds + (4 * lg + r) * 520;
            row[col[0]] = f2bf(a0[r] + bi[0]);
            row[col[1]] = f2bf(a1[r] + bi[1]);
            row[col[2]] = f2bf(a2[r] + bi[2]);
            if (zpad[0]) row[col[0] + 3] = 0;
            if (zpad[1]) row[col[1] + 3] = 0;
            if (zpad[2]) row[col[2] + 3] = 0;
        }
        asm volatile("s_waitcnt lgkmcnt(0)" ::: "memory");
        __builtin_amdgcn_s_barrier();

        // copy out: 16 rows x 64 x 16B units, contiguous in C
        u32x4* cg = (u32x4*)(C + (m0 + mt * 16) * 512);
        #pragma unroll
        for (int i = 0; i < 2; ++i) {
            int idx = tid + 512 * i;
            int row = idx >> 6, un = idx & 63;
            const u32x4* src = (const u32x4*)(D_lds + row * 520 + un * 8);
            cg[idx] = *src;                       // fire-and-forget
        }
    }
}

// r13 recurrence structure; gi is gate-interleaved bf16 -> ONE aligned 8B
// dwordx2 prefetch load per step (no D16 loads); unpack = 2 shifts + AND.
// hout back to fp32 dword stores. Matvec f32x2 (v_pk_fma_f32), DPP reduce,
// [4][36] LDS h dbuf, 4-deep prefetch, ONE raw s_barrier/step, lgkm drain.
__global__ __launch_bounds__(512, 2) void gru_seq(const unsigned short* __restrict__ gi,
                                                  const float* __restrict__ Whh,
                                                  const float* __restrict__ bhh,
                                                  float* __restrict__ hout)
{
    __shared__ alignas(16) float hbuf[2][4][36];

    const int tid = threadIdx.x;
    const int b = blockIdx.x;
    const int w = tid >> 6, lane = tid & 63;
    const int j = 16 * w + (lane >> 2);
    const int s = lane & 3;
    const bool fin = (s == 0);

    f32x2 wr2[16], wz2[16], wn2[16];
    {
        const float4* p0 = (const float4*)(Whh + (size_t)j * 128 + s * 32);
        const float4* p1 = (const float4*)(Whh + (size_t)(128 + j) * 128 + s * 32);
        const float4* p2 = (const float4*)(Whh + (size_t)(256 + j) * 128 + s * 32);
        #pragma unroll
        for (int q = 0; q < 8; ++q) {
            float4 v0 = p0[q], v1 = p1[q], v2 = p2[q];
            wr2[2*q]   = f32x2{v0.x, v0.y};
            wr2[2*q+1] = f32x2{v0.z, v0.w};
            wz2[2*q]   = f32x2{v1.x, v1.y};
            wz2[2*q+1] = f32x2{v1.z, v1.w};
            wn2[2*q]   = f32x2{v2.x, v2.y};
            wn2[2*q+1] = f32x2{v2.z, v2.w};
        }
    }
    const float br = bhh[j], bz = bhh[128 + j], bn = bhh[256 + j];

    if (tid < H_) hbuf[0][tid >> 5][tid & 31] = 0.f;
    __syncthreads();

    // gi row = 512 ushort (1KB); this thread's gate pair at byte j*8
    const char* gipb = (const char*)gi + (size_t)b * T_ * 1024 + (size_t)j * 8;
    float* hop = hout + (size_t)b * T_ * H_ + j;

    u32x2 g0 = {0,0}, g1 = g0, g2 = g0, g3 = g0;
    if (fin) {
        g0 = *(const u32x2*)(gipb + 0 * 1024);
        g1 = *(const u32x2*)(gipb + 1 * 1024);
        g2 = *(const u32x2*)(gipb + 2 * 1024);
        g3 = *(const u32x2*)(gipb + 3 * 1024);
    }
    float hprev = 0.f;

    auto step = [&](int t, u32x2& gc) {
        const int p = t & 1;
        const float4* hv = (const float4*)(&hbuf[p][s][0]);
        f32x2 pr2 = {0.f, 0.f}, pz2 = pr2, pn2 = pr2;
        #pragma unroll
        for (int q = 0; q < 8; ++q) {
            float4 h4 = hv[q];
            f32x2 ha = {h4.x, h4.y};
            f32x2 hb = {h4.z, h4.w};
            pr2 += wr2[2*q] * ha;  pr2 += wr2[2*q+1] * hb;
            pz2 += wz2[2*q] * ha;  pz2 += wz2[2*q+1] * hb;
            pn2 += wn2[2*q] * ha;  pn2 += wn2[2*q+1] * hb;
        }
        float pr = dpp_red2(pr2[0] + pr2[1]);
        float pz = dpp_red2(pz2[0] + pz2[1]);
        float pn = dpp_red2(pn2[0] + pn2[1]);

        if (fin) {
            float gr = __builtin_bit_cast(float, gc[0] << 16);
            float gz = __builtin_bit_cast(float, gc[0] & 0xFFFF0000u);
            float gn = __builtin_bit_cast(float, gc[1] << 16);
            float r  = sigm(gr + pr + br);
            float z  = sigm(gz + pz + bz);
            float nn = tanh_f(gn + r * (pn + bn));
            float h  = (1.f - z) * nn + z * hprev;
            hprev = h;
            hbuf[p ^ 1][j >> 5][j & 31] = h;
            hop[(size_t)t * H_] = h;                     // fire-and-forget
            int tn = (t + 4 < T_) ? t + 4 : T_ - 1;
            gc = *(const u32x2*)(gipb + (size_t)tn * 1024);
        }
        asm volatile("s_waitcnt lgkmcnt(0)" ::: "memory");
        __builtin_amdgcn_s_barrier();
    };

    for (int t = 0; t < T_; t += 4) {
        step(t + 0, g0);
        step(t + 1, g1);
        step(t + 2, g2);
        step(t + 3, g3);
    }
}

// One wave per sample (fp32 h2): a = h2·W1[reg]+b1; SiLU; corr = a·W2[reg]+b2
__global__ __launch_bounds__(256) void head_k(const float* __restrict__ h2,
                                              const float* __restrict__ x,
                                              const int* __restrict__ regime,
                                              const float* __restrict__ W1,
                                              const float* __restrict__ b1,
                                              const float* __restrict__ W2,
                                              const float* __restrict__ b2,
                                              const float* __restrict__ lag_scale,
                                              const float* __restrict__ lag_bias,
                                              float* __restrict__ out)
{
    __shared__ alignas(16) float hrow[4][128];
    const int tid = threadIdx.x;
    const int wv = tid >> 6, lane = tid & 63;
    const size_t s = (size_t)blockIdx.x * 4 + wv;
    const int reg = regime[s];

    if (lane < 32)
        ((float4*)hrow[wv])[lane] = ((const float4*)(h2 + s * H_))[lane];
    __syncthreads();

    float acc = b1[reg * K_ + lane];
    const float* Wp = W1 + (size_t)reg * H_ * K_ + lane;
    const float4* h4p = (const float4*)hrow[wv];
    #pragma unroll
    for (int q = 0; q < 32; ++q) {
        float4 h4 = h4p[q];
        acc += h4.x * Wp[(4 * q + 0) * K_];
        acc += h4.y * Wp[(4 * q + 1) * K_];
        acc += h4.z * Wp[(4 * q + 2) * K_];
        acc += h4.w * Wp[(4 * q + 3) * K_];
    }
    float silu = acc * sigm(acc);
    float v = silu * W2[reg * K_ + lane];
    #pragma unroll
    for (int m = 1; m < 64; m <<= 1) v += __shfl_xor(v, m);
    if (lane == 0) {
        float lag = lag_scale[0] * x[s * F_] + lag_bias[0];
        out[s] = lag + v + b2[reg];
    }
}

extern "C" void kernel_launch(void* const* d_in, const int* in_sizes, int n_in,
                              void* d_out, int out_size, void* d_ws, size_t ws_size,
                              hipStream_t stream) {
    const float* x         = (const float*)d_in[0];
    const int*   regime    = (const int*)d_in[1];
    const float* lag_scale = (const float*)d_in[2];
    const float* lag_bias  = (const float*)d_in[3];
    const float* Wih0      = (const float*)d_in[4];
    const float* Whh0      = (const float*)d_in[5];
    const float* bih0      = (const float*)d_in[6];
    const float* bhh0      = (const float*)d_in[7];
    const float* Wih1      = (const float*)d_in[8];
    const float* Whh1      = (const float*)d_in[9];
    const float* bih1      = (const float*)d_in[10];
    const float* bhh1      = (const float*)d_in[11];
    const float* W1        = (const float*)d_in[12];
    const float* b1        = (const float*)d_in[13];
    const float* W2        = (const float*)d_in[14];
    const float* b2        = (const float*)d_in[15];
    float* out = (float*)d_out;

    const size_t NT = (size_t)B_ * T_;                        // 131072
    const size_t need = NT * 512 * 2 + NT * H_ * 4;           // 134MB + 67MB
    if (ws_size < need) {
        hipMemsetAsync(d_out, 0x7F, (size_t)out_size * 4, stream);
        return;
    }
    unsigned short* gi = (unsigned short*)d_ws;               // [m][128][4] bf16
    float* hb = (float*)(gi + NT * 512);                      // fp32 h

    const int gblocks = (int)(NT / 128);                      // 1024
    gemm_gi_mfma<<<gblocks, 512, 0, stream>>>(x, Wih0, bih0, gi);
    gru_seq<<<B_, 512, 0, stream>>>(gi, Whh0, bhh0, hb);
    gemm_gi_mfma<<<gblocks, 512, 0, stream>>>(hb, Wih1, bih1, gi);
    gru_seq<<<B_, 512, 0, stream>>>(gi, Whh1, bhh1, hb);
    head_k<<<(int)(NT / 4), 256, 0, stream>>>(hb, x, regime, W1, b1, W2, b2,
                                              lag_scale, lag_bias, out);
}

// Round 16
// 874.481 us; speedup vs baseline: 1.0826x; 1.0013x over previous
//
#include <hip/hip_runtime.h>
#include <hip/hip_bf16.h>
#include <cstdint>

#define B_ 256
#define T_ 512
#define F_ 128
#define H_ 128
#define G3_ 384
#define R_ 8
#define K_ 64

typedef __attribute__((ext_vector_type(8))) short short8_t;
typedef __attribute__((ext_vector_type(4))) float f32x4;
typedef __attribute__((ext_vector_type(2))) float f32x2;
typedef __attribute__((ext_vector_type(4))) unsigned int u32x4;
typedef __attribute__((ext_vector_type(2))) unsigned int u32x2;

__device__ __forceinline__ float sigm(float x) { return 1.f / (1.f + __expf(-x)); }
__device__ __forceinline__ float tanh_f(float x) { return 1.f - 2.f / (1.f + __expf(2.f * x)); }
__device__ __forceinline__ unsigned short f2bf(float f) {
    uint32_t u = __builtin_bit_cast(uint32_t, f);
    return (unsigned short)((u + 0x7FFFu + ((u >> 16) & 1u)) >> 16);
}
__device__ __forceinline__ short8_t pack8(float4 a, float4 b) {
    short8_t v;
    v[0] = (short)f2bf(a.x); v[1] = (short)f2bf(a.y);
    v[2] = (short)f2bf(a.z); v[3] = (short)f2bf(a.w);
    v[4] = (short)f2bf(b.x); v[5] = (short)f2bf(b.y);
    v[6] = (short)f2bf(b.z); v[7] = (short)f2bf(b.w);
    return v;
}

// Quad-local butterfly adds on the VALU pipe (DPP quad_perm).
__device__ __forceinline__ float dpp_red2(float x) {
    int a = __builtin_amdgcn_mov_dpp(__builtin_bit_cast(int, x), 0xB1, 0xF, 0xF, true);
    x += __builtin_bit_cast(float, a);
    int b = __builtin_amdgcn_mov_dpp(__builtin_bit_cast(int, x), 0x4E, 0xF, 0xF, true);
    x += __builtin_bit_cast(float, b);
    return x;
}

// MFMA GEMM producing GATE-INTERLEAVED bf16 gi: C[m][j][g], g in {r,z,n,pad},
// row = 512 ushort (1KB). A fp32. D restaged through LDS strip [16][520]
// (interleave applied at restage); copy-out is contiguous dwordx4 stores.
__global__ __launch_bounds__(512, 2) void gemm_gi_mfma(const float* __restrict__ A,
                                                       const float* __restrict__ W,
                                                       const float* __restrict__ bias,
                                                       unsigned short* __restrict__ C)
{
    __shared__ alignas(16) unsigned short A_lds[128 * 128];   // bf16, swizzled
    __shared__ alignas(16) unsigned short D_lds[16 * 520];    // interleaved strip

    const int tid = threadIdx.x;
    const int wv = tid >> 6, lane = tid & 63;
    const int lc = lane & 15, lg = lane >> 4;
    const size_t m0 = (size_t)blockIdx.x * 128;

    short8_t bf[3][4];
    float bi[3];
    int col[3];          // interleaved column j*4+g for each u
    bool zpad[3];        // this (wv,u) also zeroes the pad slot (g==0 owners)
    #pragma unroll
    for (int u = 0; u < 3; ++u) {
        const int n = 48 * wv + 16 * u + lc;
        const int g = n >> 7, j = n & 127;
        col[u] = j * 4 + g;
        zpad[u] = (g == 0);
        bi[u] = bias[n];
        #pragma unroll
        for (int ks = 0; ks < 4; ++ks) {
            const float4* wp = (const float4*)(W + (size_t)n * 128 + ks * 32 + lg * 8);
            bf[u][ks] = pack8(wp[0], wp[1]);
        }
    }

    {
        const int m = tid >> 2, kq = tid & 3;
        const float4* ap = (const float4*)(A + (m0 + m) * 128 + kq * 32);
        float4 v0 = ap[0], v1 = ap[1], v2 = ap[2], v3 = ap[3];
        float4 v4 = ap[4], v5 = ap[5], v6 = ap[6], v7 = ap[7];
        char* base = (char*)A_lds;
        const int bb = m * 256 + kq * 64, sw = (m & 7) << 4;
        *(short8_t*)(base + ((bb +  0) ^ sw)) = pack8(v0, v1);
        *(short8_t*)(base + ((bb + 16) ^ sw)) = pack8(v2, v3);
        *(short8_t*)(base + ((bb + 32) ^ sw)) = pack8(v4, v5);
        *(short8_t*)(base + ((bb + 48) ^ sw)) = pack8(v6, v7);
    }
    __syncthreads();

    const char* Ab = (const char*)A_lds;
    for (int mt = 0; mt < 8; ++mt) {
        short8_t af0 = *(const short8_t*)(Ab + (((mt * 16 + lc) * 256 +  0 + lg * 16) ^ ((lc & 7) << 4)));
        short8_t af1 = *(const short8_t*)(Ab + (((mt * 16 + lc) * 256 + 64 + lg * 16) ^ ((lc & 7) << 4)));
        short8_t af2 = *(const short8_t*)(Ab + (((mt * 16 + lc) * 256 + 128 + lg * 16) ^ ((lc & 7) << 4)));
        short8_t af3 = *(const short8_t*)(Ab + (((mt * 16 + lc) * 256 + 192 + lg * 16) ^ ((lc & 7) << 4)));
        f32x4 a0 = {0.f, 0.f, 0.f, 0.f}, a1 = a0, a2 = a0;
        a0 = __builtin_amdgcn_mfma_f32_16x16x32_bf16(af0, bf[0][0], a0, 0, 0, 0);
        a1 = __builtin_amdgcn_mfma_f32_16x16x32_bf16(af0, bf[1][0], a1, 0, 0, 0);
        a2 = __builtin_amdgcn_mfma_f32_16x16x32_bf16(af0, bf[2][0], a2, 0, 0, 0);
        a0 = __builtin_amdgcn_mfma_f32_16x16x32_bf16(af1, bf[0][1], a0, 0, 0, 0);
        a1 = __builtin_amdgcn_mfma_f32_16x16x32_bf16(af1, bf[1][1], a1, 0, 0, 0);
        a2 = __builtin_amdgcn_mfma_f32_16x16x32_bf16(af1, bf[2][1], a2, 0, 0, 0);
        a0 = __builtin_amdgcn_mfma_f32_16x16x32_bf16(af2, bf[0][2], a0, 0, 0, 0);
        a1 = __builtin_amdgcn_mfma_f32_16x16x32_bf16(af2, bf[1][2], a1, 0, 0, 0);
        a2 = __builtin_amdgcn_mfma_f32_16x16x32_bf16(af2, bf[2][2], a2, 0, 0, 0);
        a0 = __builtin_amdgcn_mfma_f32_16x16x32_bf16(af3, bf[0][3], a0, 0, 0, 0);
        a1 = __builtin_amdgcn_mfma_f32_16x16x32_bf16(af3, bf[1][3], a1, 0, 0, 0);
        a2 = __builtin_amdgcn_mfma_f32_16x16x32_bf16(af3, bf[2][3], a2, 0, 0, 0);

        asm volatile("s_waitcnt lgkmcnt(0)" ::: "memory");
        __builtin_amdgcn_s_barrier();
        #pragma unroll
        for (int r = 0; r < 4; ++r) {
            unsigned short* row = D_lds + (4 * lg + r) * 520;
            row[col[0]] = f2bf(a0[r] + bi[0]);
            row[col[1]] = f2bf(a1[r] + bi[1]);
            row[col[2]] = f2bf(a2[r] + bi[2]);
            if (zpad[0]) row[col[0] + 3] = 0;
            if (zpad[1]) row[col[1] + 3] = 0;
            if (zpad[2]) row[col[2] + 3] = 0;
        }
        asm volatile("s_waitcnt lgkmcnt(0)" ::: "memory");
        __builtin_amdgcn_s_barrier();

        // copy out: 16 rows x 64 x 16B units, contiguous in C
        u32x4* cg = (u32x4*)(C + (m0 + mt * 16) * 512);
        #pragma unroll
        for (int i = 0; i < 2; ++i) {
            int idx = tid + 512 * i;
            int row = idx >> 6, un = idx & 63;
            const u32x4* src = (const u32x4*)(D_lds + row * 520 + un * 8);
            cg[idx] = *src;                       // fire-and-forget
        }
    }
}

// r15 recurrence, ONE change: the per-step barrier uses a SCOPED LDS-ONLY
// fence instead of an asm "memory" clobber. The clobber forced the compiler
// to reload every scratch/non-LDS-resident value (the 96-float weight set
// doesn't fit VGPR_Count=68 -> lives in scratch) EVERY step — the 2x VALU
// issue inflation seen since r2. fence(workgroup,"local") still orders the
// h double-buffer ds ops (emits lgkmcnt wait) but leaves global/private
// memory un-clobbered; vmcnt stays un-drained (fire-and-forget preserved).
__global__ __launch_bounds__(512, 2) void gru_seq(const unsigned short* __restrict__ gi,
                                                  const float* __restrict__ Whh,
                                                  const float* __restrict__ bhh,
                                                  float* __restrict__ hout)
{
    __shared__ alignas(16) float hbuf[2][4][36];

    const int tid = threadIdx.x;
    const int b = blockIdx.x;
    const int w = tid >> 6, lane = tid & 63;
    const int j = 16 * w + (lane >> 2);
    const int s = lane & 3;
    const bool fin = (s == 0);

    f32x2 wr2[16], wz2[16], wn2[16];
    {
        const float4* p0 = (const float4*)(Whh + (size_t)j * 128 + s * 32);
        const float4* p1 = (const float4*)(Whh + (size_t)(128 + j) * 128 + s * 32);
        const float4* p2 = (const float4*)(Whh + (size_t)(256 + j) * 128 + s * 32);
        #pragma unroll
        for (int q = 0; q < 8; ++q) {
            float4 v0 = p0[q], v1 = p1[q], v2 = p2[q];
            wr2[2*q]   = f32x2{v0.x, v0.y};
            wr2[2*q+1] = f32x2{v0.z, v0.w};
            wz2[2*q]   = f32x2{v1.x, v1.y};
            wz2[2*q+1] = f32x2{v1.z, v1.w};
            wn2[2*q]   = f32x2{v2.x, v2.y};
            wn2[2*q+1] = f32x2{v2.z, v2.w};
        }
    }
    const float br = bhh[j], bz = bhh[128 + j], bn = bhh[256 + j];

    if (tid < H_) hbuf[0][tid >> 5][tid & 31] = 0.f;
    __syncthreads();

    // gi row = 512 ushort (1KB); this thread's gate pair at byte j*8
    const char* gipb = (const char*)gi + (size_t)b * T_ * 1024 + (size_t)j * 8;
    float* hop = hout + (size_t)b * T_ * H_ + j;

    u32x2 g0 = {0,0}, g1 = g0, g2 = g0, g3 = g0;
    if (fin) {
        g0 = *(const u32x2*)(gipb + 0 * 1024);
        g1 = *(const u32x2*)(gipb + 1 * 1024);
        g2 = *(const u32x2*)(gipb + 2 * 1024);
        g3 = *(const u32x2*)(gipb + 3 * 1024);
    }
    float hprev = 0.f;

    auto step = [&](int t, u32x2& gc) {
        const int p = t & 1;
        const float4* hv = (const float4*)(&hbuf[p][s][0]);
        f32x2 pr2 = {0.f, 0.f}, pz2 = pr2, pn2 = pr2;
        #pragma unroll
        for (int q = 0; q < 8; ++q) {
            float4 h4 = hv[q];
            f32x2 ha = {h4.x, h4.y};
            f32x2 hb = {h4.z, h4.w};
            pr2 += wr2[2*q] * ha;  pr2 += wr2[2*q+1] * hb;
            pz2 += wz2[2*q] * ha;  pz2 += wz2[2*q+1] * hb;
            pn2 += wn2[2*q] * ha;  pn2 += wn2[2*q+1] * hb;
        }
        float pr = dpp_red2(pr2[0] + pr2[1]);
        float pz = dpp_red2(pz2[0] + pz2[1]);
        float pn = dpp_red2(pn2[0] + pn2[1]);

        if (fin) {
            float gr = __builtin_bit_cast(float, gc[0] << 16);
            float gz = __builtin_bit_cast(float, gc[0] & 0xFFFF0000u);
            float gn = __builtin_bit_cast(float, gc[1] << 16);
            float r  = sigm(gr + pr + br);
            float z  = sigm(gz + pz + bz);
            float nn = tanh_f(gn + r * (pn + bn));
            float h  = (1.f - z) * nn + z * hprev;
            hprev = h;
            hbuf[p ^ 1][j >> 5][j & 31] = h;
            hop[(size_t)t * H_] = h;                     // fire-and-forget
            int tn = (t + 4 < T_) ? t + 4 : T_ - 1;
            gc = *(const u32x2*)(gipb + (size_t)tn * 1024);
        }
        // LDS-only ordering: release our ds_write, barrier, acquire theirs.
        // No global/private clobber -> no per-step scratch reloads.
        __builtin_amdgcn_fence(__ATOMIC_RELEASE, "workgroup", "local");
        __builtin_amdgcn_s_barrier();
        __builtin_amdgcn_fence(__ATOMIC_ACQUIRE, "workgroup", "local");
    };

    for (int t = 0; t < T_; t += 4) {
        step(t + 0, g0);
        step(t + 1, g1);
        step(t + 2, g2);
        step(t + 3, g3);
    }
}

// One wave per sample (fp32 h2): a = h2·W1[reg]+b1; SiLU; corr = a·W2[reg]+b2
__global__ __launch_bounds__(256) void head_k(const float* __restrict__ h2,
                                              const float* __restrict__ x,
                                              const int* __restrict__ regime,
                                              const float* __restrict__ W1,
                                              const float* __restrict__ b1,
                                              const float* __restrict__ W2,
                                              const float* __restrict__ b2,
                                              const float* __restrict__ lag_scale,
                                              const float* __restrict__ lag_bias,
                                              float* __restrict__ out)
{
    __shared__ alignas(16) float hrow[4][128];
    const int tid = threadIdx.x;
    const int wv = tid >> 6, lane = tid & 63;
    const size_t s = (size_t)blockIdx.x * 4 + wv;
    const int reg = regime[s];

    if (lane < 32)
        ((float4*)hrow[wv])[lane] = ((const float4*)(h2 + s * H_))[lane];
    __syncthreads();

    float acc = b1[reg * K_ + lane];
    const float* Wp = W1 + (size_t)reg * H_ * K_ + lane;
    const float4* h4p = (const float4*)hrow[wv];
    #pragma unroll
    for (int q = 0; q < 32; ++q) {
        float4 h4 = h4p[q];
        acc += h4.x * Wp[(4 * q + 0) * K_];
        acc += h4.y * Wp[(4 * q + 1) * K_];
        acc += h4.z * Wp[(4 * q + 2) * K_];
        acc += h4.w * Wp[(4 * q + 3) * K_];
    }
    float silu = acc * sigm(acc);
    float v = silu * W2[reg * K_ + lane];
    #pragma unroll
    for (int m = 1; m < 64; m <<= 1) v += __shfl_xor(v, m);
    if (lane == 0) {
        float lag = lag_scale[0] * x[s * F_] + lag_bias[0];
        out[s] = lag + v + b2[reg];
    }
}

extern "C" void kernel_launch(void* const* d_in, const int* in_sizes, int n_in,
                              void* d_out, int out_size, void* d_ws, size_t ws_size,
                              hipStream_t stream) {
    const float* x         = (const float*)d_in[0];
    const int*   regime    = (const int*)d_in[1];
    const float* lag_scale = (const float*)d_in[2];
    const float* lag_bias  = (const float*)d_in[3];
    const float* Wih0      = (const float*)d_in[4];
    const float* Whh0      = (const float*)d_in[5];
    const float* bih0      = (const float*)d_in[6];
    const float* bhh0      = (const float*)d_in[7];
    const float* Wih1      = (const float*)d_in[8];
    const float* Whh1      = (const float*)d_in[9];
    const float* bih1      = (const float*)d_in[10];
    const float* bhh1      = (const float*)d_in[11];
    const float* W1        = (const float*)d_in[12];
    const float* b1        = (const float*)d_in[13];
    const float* W2        = (const float*)d_in[14];
    const float* b2        = (const float*)d_in[15];
    float* out = (float*)d_out;

    const size_t NT = (size_t)B_ * T_;                        // 131072
    const size_t need = NT * 512 * 2 + NT * H_ * 4;           // 134MB + 67MB
    if (ws_size < need) {
        hipMemsetAsync(d_out, 0x7F, (size_t)out_size * 4, stream);
        return;
    }
    unsigned short* gi = (unsigned short*)d_ws;               // [m][128][4] bf16
    float* hb = (float*)(gi + NT * 512);                      // fp32 h

    const int gblocks = (int)(NT / 128);                      // 1024
    gemm_gi_mfma<<<gblocks, 512, 0, stream>>>(x, Wih0, bih0, gi);
    gru_seq<<<B_, 512, 0, stream>>>(gi, Whh0, bhh0, hb);
    gemm_gi_mfma<<<gblocks, 512, 0, stream>>>(hb, Wih1, bih1, gi);
    gru_seq<<<B_, 512, 0, stream>>>(gi, Whh1, bhh1, hb);
    head_k<<<(int)(NT / 4), 256, 0, stream>>>(hb, x, regime, W1, b1, W2, b2,
                                              lag_scale, lag_bias, out);
}

// Round 17
// 863.179 us; speedup vs baseline: 1.0967x; 1.0131x over previous
//
#include <hip/hip_runtime.h>
#include <hip/hip_bf16.h>
#include <cstdint>

#define B_ 256
#define T_ 512
#define F_ 128
#define H_ 128
#define G3_ 384
#define R_ 8
#define K_ 64

typedef __attribute__((ext_vector_type(8))) short short8_t;
typedef __attribute__((ext_vector_type(4))) float f32x4;
typedef __attribute__((ext_vector_type(2))) float f32x2;
typedef __attribute__((ext_vector_type(4))) unsigned int u32x4;
typedef __attribute__((ext_vector_type(2))) unsigned int u32x2;

__device__ __forceinline__ float sigm(float x) { return 1.f / (1.f + __expf(-x)); }
__device__ __forceinline__ float tanh_f(float x) { return 1.f - 2.f / (1.f + __expf(2.f * x)); }
__device__ __forceinline__ unsigned short f2bf(float f) {
    uint32_t u = __builtin_bit_cast(uint32_t, f);
    return (unsigned short)((u + 0x7FFFu + ((u >> 16) & 1u)) >> 16);
}
__device__ __forceinline__ short8_t pack8(float4 a, float4 b) {
    short8_t v;
    v[0] = (short)f2bf(a.x); v[1] = (short)f2bf(a.y);
    v[2] = (short)f2bf(a.z); v[3] = (short)f2bf(a.w);
    v[4] = (short)f2bf(b.x); v[5] = (short)f2bf(b.y);
    v[6] = (short)f2bf(b.z); v[7] = (short)f2bf(b.w);
    return v;
}

// Quad-local butterfly adds on the VALU pipe (DPP quad_perm).
__device__ __forceinline__ float dpp_red2(float x) {
    int a = __builtin_amdgcn_mov_dpp(__builtin_bit_cast(int, x), 0xB1, 0xF, 0xF, true);
    x += __builtin_bit_cast(float, a);
    int b = __builtin_amdgcn_mov_dpp(__builtin_bit_cast(int, x), 0x4E, 0xF, 0xF, true);
    x += __builtin_bit_cast(float, b);
    return x;
}

// MFMA GEMM producing GATE-INTERLEAVED bf16 gi: C[m][j][g], g in {r,z,n,pad},
// row = 512 ushort (1KB). A fp32. D restaged through LDS strip [16][520]
// (interleave applied at restage); copy-out is contiguous dwordx4 stores.
__global__ __launch_bounds__(512, 2) void gemm_gi_mfma(const float* __restrict__ A,
                                                       const float* __restrict__ W,
                                                       const float* __restrict__ bias,
                                                       unsigned short* __restrict__ C)
{
    __shared__ alignas(16) unsigned short A_lds[128 * 128];   // bf16, swizzled
    __shared__ alignas(16) unsigned short D_lds[16 * 520];    // interleaved strip

    const int tid = threadIdx.x;
    const int wv = tid >> 6, lane = tid & 63;
    const int lc = lane & 15, lg = lane >> 4;
    const size_t m0 = (size_t)blockIdx.x * 128;

    short8_t bf[3][4];
    float bi[3];
    int col[3];          // interleaved column j*4+g for each u
    bool zpad[3];        // this (wv,u) also zeroes the pad slot (g==0 owners)
    #pragma unroll
    for (int u = 0; u < 3; ++u) {
        const int n = 48 * wv + 16 * u + lc;
        const int g = n >> 7, j = n & 127;
        col[u] = j * 4 + g;
        zpad[u] = (g == 0);
        bi[u] = bias[n];
        #pragma unroll
        for (int ks = 0; ks < 4; ++ks) {
            const float4* wp = (const float4*)(W + (size_t)n * 128 + ks * 32 + lg * 8);
            bf[u][ks] = pack8(wp[0], wp[1]);
        }
    }

    {
        const int m = tid >> 2, kq = tid & 3;
        const float4* ap = (const float4*)(A + (m0 + m) * 128 + kq * 32);
        float4 v0 = ap[0], v1 = ap[1], v2 = ap[2], v3 = ap[3];
        float4 v4 = ap[4], v5 = ap[5], v6 = ap[6], v7 = ap[7];
        char* base = (char*)A_lds;
        const int bb = m * 256 + kq * 64, sw = (m & 7) << 4;
        *(short8_t*)(base + ((bb +  0) ^ sw)) = pack8(v0, v1);
        *(short8_t*)(base + ((bb + 16) ^ sw)) = pack8(v2, v3);
        *(short8_t*)(base + ((bb + 32) ^ sw)) = pack8(v4, v5);
        *(short8_t*)(base + ((bb + 48) ^ sw)) = pack8(v6, v7);
    }
    __syncthreads();

    const char* Ab = (const char*)A_lds;
    for (int mt = 0; mt < 8; ++mt) {
        short8_t af0 = *(const short8_t*)(Ab + (((mt * 16 + lc) * 256 +  0 + lg * 16) ^ ((lc & 7) << 4)));
        short8_t af1 = *(const short8_t*)(Ab + (((mt * 16 + lc) * 256 + 64 + lg * 16) ^ ((lc & 7) << 4)));
        short8_t af2 = *(const short8_t*)(Ab + (((mt * 16 + lc) * 256 + 128 + lg * 16) ^ ((lc & 7) << 4)));
        short8_t af3 = *(const short8_t*)(Ab + (((mt * 16 + lc) * 256 + 192 + lg * 16) ^ ((lc & 7) << 4)));
        f32x4 a0 = {0.f, 0.f, 0.f, 0.f}, a1 = a0, a2 = a0;
        a0 = __builtin_amdgcn_mfma_f32_16x16x32_bf16(af0, bf[0][0], a0, 0, 0, 0);
        a1 = __builtin_amdgcn_mfma_f32_16x16x32_bf16(af0, bf[1][0], a1, 0, 0, 0);
        a2 = __builtin_amdgcn_mfma_f32_16x16x32_bf16(af0, bf[2][0], a2, 0, 0, 0);
        a0 = __builtin_amdgcn_mfma_f32_16x16x32_bf16(af1, bf[0][1], a0, 0, 0, 0);
        a1 = __builtin_amdgcn_mfma_f32_16x16x32_bf16(af1, bf[1][1], a1, 0, 0, 0);
        a2 = __builtin_amdgcn_mfma_f32_16x16x32_bf16(af1, bf[2][1], a2, 0, 0, 0);
        a0 = __builtin_amdgcn_mfma_f32_16x16x32_bf16(af2, bf[0][2], a0, 0, 0, 0);
        a1 = __builtin_amdgcn_mfma_f32_16x16x32_bf16(af2, bf[1][2], a1, 0, 0, 0);
        a2 = __builtin_amdgcn_mfma_f32_16x16x32_bf16(af2, bf[2][2], a2, 0, 0, 0);
        a0 = __builtin_amdgcn_mfma_f32_16x16x32_bf16(af3, bf[0][3], a0, 0, 0, 0);
        a1 = __builtin_amdgcn_mfma_f32_16x16x32_bf16(af3, bf[1][3], a1, 0, 0, 0);
        a2 = __builtin_amdgcn_mfma_f32_16x16x32_bf16(af3, bf[2][3], a2, 0, 0, 0);

        asm volatile("s_waitcnt lgkmcnt(0)" ::: "memory");
        __builtin_amdgcn_s_barrier();
        #pragma unroll
        for (int r = 0; r < 4; ++r) {
            unsigned short* row = D_lds + (4 * lg + r) * 520;
            row[col[0]] = f2bf(a0[r] + bi[0]);
            row[col[1]] = f2bf(a1[r] + bi[1]);
            row[col[2]] = f2bf(a2[r] + bi[2]);
            if (zpad[0]) row[col[0] + 3] = 0;
            if (zpad[1]) row[col[1] + 3] = 0;
            if (zpad[2]) row[col[2] + 3] = 0;
        }
        asm volatile("s_waitcnt lgkmcnt(0)" ::: "memory");
        __builtin_amdgcn_s_barrier();

        // copy out: 16 rows x 64 x 16B units, contiguous in C
        u32x4* cg = (u32x4*)(C + (m0 + mt * 16) * 512);
        #pragma unroll
        for (int i = 0; i < 2; ++i) {
            int idx = tid + 512 * i;
            int row = idx >> 6, un = idx & 63;
            const u32x4* src = (const u32x4*)(D_lds + row * 520 + un * 8);
            cg[idx] = *src;                       // fire-and-forget
        }
    }
}

// r16 recurrence, ONE change: matvec written as EXPLICIT __builtin_fmaf
// (guaranteed v_fma_f32 formation). Evidence: measured ~255 VALU insts/wave/
// step across r5/r8/r9 matches un-contracted mul+add (96*2 + ~50 overhead),
// not the ~146 of a contracted build. 6 independent 16-deep chains.
__global__ __launch_bounds__(512, 2) void gru_seq(const unsigned short* __restrict__ gi,
                                                  const float* __restrict__ Whh,
                                                  const float* __restrict__ bhh,
                                                  float* __restrict__ hout)
{
    __shared__ alignas(16) float hbuf[2][4][36];

    const int tid = threadIdx.x;
    const int b = blockIdx.x;
    const int w = tid >> 6, lane = tid & 63;
    const int j = 16 * w + (lane >> 2);
    const int s = lane & 3;
    const bool fin = (s == 0);

    // per-thread weights: rows j (r), 128+j (z), 256+j (n), cols [32s,32s+32)
    float wr_[32], wz_[32], wn_[32];
    {
        const float4* p0 = (const float4*)(Whh + (size_t)j * 128 + s * 32);
        const float4* p1 = (const float4*)(Whh + (size_t)(128 + j) * 128 + s * 32);
        const float4* p2 = (const float4*)(Whh + (size_t)(256 + j) * 128 + s * 32);
        #pragma unroll
        for (int q = 0; q < 8; ++q) {
            float4 v0 = p0[q], v1 = p1[q], v2 = p2[q];
            wr_[4*q+0]=v0.x; wr_[4*q+1]=v0.y; wr_[4*q+2]=v0.z; wr_[4*q+3]=v0.w;
            wz_[4*q+0]=v1.x; wz_[4*q+1]=v1.y; wz_[4*q+2]=v1.z; wz_[4*q+3]=v1.w;
            wn_[4*q+0]=v2.x; wn_[4*q+1]=v2.y; wn_[4*q+2]=v2.z; wn_[4*q+3]=v2.w;
        }
    }
    const float br = bhh[j], bz = bhh[128 + j], bn = bhh[256 + j];

    if (tid < H_) hbuf[0][tid >> 5][tid & 31] = 0.f;
    __syncthreads();

    // gi row = 512 ushort (1KB); this thread's gate pair at byte j*8
    const char* gipb = (const char*)gi + (size_t)b * T_ * 1024 + (size_t)j * 8;
    float* hop = hout + (size_t)b * T_ * H_ + j;

    u32x2 g0 = {0,0}, g1 = g0, g2 = g0, g3 = g0;
    if (fin) {
        g0 = *(const u32x2*)(gipb + 0 * 1024);
        g1 = *(const u32x2*)(gipb + 1 * 1024);
        g2 = *(const u32x2*)(gipb + 2 * 1024);
        g3 = *(const u32x2*)(gipb + 3 * 1024);
    }
    float hprev = 0.f;

    auto step = [&](int t, u32x2& gc) {
        const int p = t & 1;
        const float4* hv = (const float4*)(&hbuf[p][s][0]);
        float4 h0 = hv[0], h1 = hv[1], h2 = hv[2], h3 = hv[3];
        float4 h4 = hv[4], h5 = hv[5], h6 = hv[6], h7 = hv[7];
        float hh[32] = {h0.x,h0.y,h0.z,h0.w, h1.x,h1.y,h1.z,h1.w,
                        h2.x,h2.y,h2.z,h2.w, h3.x,h3.y,h3.z,h3.w,
                        h4.x,h4.y,h4.z,h4.w, h5.x,h5.y,h5.z,h5.w,
                        h6.x,h6.y,h6.z,h6.w, h7.x,h7.y,h7.z,h7.w};
        // 6 independent FMA chains (2 per gate), explicit v_fma_f32
        float pra = 0.f, prb = 0.f, pza = 0.f, pzb = 0.f, pna = 0.f, pnb = 0.f;
        #pragma unroll
        for (int e = 0; e < 16; ++e) {
            pra = __builtin_fmaf(wr_[2*e],   hh[2*e],   pra);
            prb = __builtin_fmaf(wr_[2*e+1], hh[2*e+1], prb);
            pza = __builtin_fmaf(wz_[2*e],   hh[2*e],   pza);
            pzb = __builtin_fmaf(wz_[2*e+1], hh[2*e+1], pzb);
            pna = __builtin_fmaf(wn_[2*e],   hh[2*e],   pna);
            pnb = __builtin_fmaf(wn_[2*e+1], hh[2*e+1], pnb);
        }
        float pr = dpp_red2(pra + prb);
        float pz = dpp_red2(pza + pzb);
        float pn = dpp_red2(pna + pnb);

        if (fin) {
            float gr = __builtin_bit_cast(float, gc[0] << 16);
            float gz = __builtin_bit_cast(float, gc[0] & 0xFFFF0000u);
            float gn = __builtin_bit_cast(float, gc[1] << 16);
            float r  = sigm(gr + pr + br);
            float z  = sigm(gz + pz + bz);
            float nn = tanh_f(gn + r * (pn + bn));
            float h  = (1.f - z) * nn + z * hprev;
            hprev = h;
            hbuf[p ^ 1][j >> 5][j & 31] = h;
            hop[(size_t)t * H_] = h;                     // fire-and-forget
            int tn = (t + 4 < T_) ? t + 4 : T_ - 1;
            gc = *(const u32x2*)(gipb + (size_t)tn * 1024);
        }
        // LDS-only ordering (no global/private clobber)
        __builtin_amdgcn_fence(__ATOMIC_RELEASE, "workgroup", "local");
        __builtin_amdgcn_s_barrier();
        __builtin_amdgcn_fence(__ATOMIC_ACQUIRE, "workgroup", "local");
    };

    for (int t = 0; t < T_; t += 4) {
        step(t + 0, g0);
        step(t + 1, g1);
        step(t + 2, g2);
        step(t + 3, g3);
    }
}

// One wave per sample (fp32 h2): a = h2·W1[reg]+b1; SiLU; corr = a·W2[reg]+b2
__global__ __launch_bounds__(256) void head_k(const float* __restrict__ h2,
                                              const float* __restrict__ x,
                                              const int* __restrict__ regime,
                                              const float* __restrict__ W1,
                                              const float* __restrict__ b1,
                                              const float* __restrict__ W2,
                                              const float* __restrict__ b2,
                                              const float* __restrict__ lag_scale,
                                              const float* __restrict__ lag_bias,
                                              float* __restrict__ out)
{
    __shared__ alignas(16) float hrow[4][128];
    const int tid = threadIdx.x;
    const int wv = tid >> 6, lane = tid & 63;
    const size_t s = (size_t)blockIdx.x * 4 + wv;
    const int reg = regime[s];

    if (lane < 32)
        ((float4*)hrow[wv])[lane] = ((const float4*)(h2 + s * H_))[lane];
    __syncthreads();

    float acc = b1[reg * K_ + lane];
    const float* Wp = W1 + (size_t)reg * H_ * K_ + lane;
    const float4* h4p = (const float4*)hrow[wv];
    #pragma unroll
    for (int q = 0; q < 32; ++q) {
        float4 h4 = h4p[q];
        acc = __builtin_fmaf(h4.x, Wp[(4 * q + 0) * K_], acc);
        acc = __builtin_fmaf(h4.y, Wp[(4 * q + 1) * K_], acc);
        acc = __builtin_fmaf(h4.z, Wp[(4 * q + 2) * K_], acc);
        acc = __builtin_fmaf(h4.w, Wp[(4 * q + 3) * K_], acc);
    }
    float silu = acc * sigm(acc);
    float v = silu * W2[reg * K_ + lane];
    #pragma unroll
    for (int m = 1; m < 64; m <<= 1) v += __shfl_xor(v, m);
    if (lane == 0) {
        float lag = lag_scale[0] * x[s * F_] + lag_bias[0];
        out[s] = lag + v + b2[reg];
    }
}

extern "C" void kernel_launch(void* const* d_in, const int* in_sizes, int n_in,
                              void* d_out, int out_size, void* d_ws, size_t ws_size,
                              hipStream_t stream) {
    const float* x         = (const float*)d_in[0];
    const int*   regime    = (const int*)d_in[1];
    const float* lag_scale = (const float*)d_in[2];
    const float* lag_bias  = (const float*)d_in[3];
    const float* Wih0      = (const float*)d_in[4];
    const float* Whh0      = (const float*)d_in[5];
    const float* bih0      = (const float*)d_in[6];
    const float* bhh0      = (const float*)d_in[7];
    const float* Wih1      = (const float*)d_in[8];
    const float* Whh1      = (const float*)d_in[9];
    const float* bih1      = (const float*)d_in[10];
    const float* bhh1      = (const float*)d_in[11];
    const float* W1        = (const float*)d_in[12];
    const float* b1        = (const float*)d_in[13];
    const float* W2        = (const float*)d_in[14];
    const float* b2        = (const float*)d_in[15];
    float* out = (float*)d_out;

    const size_t NT = (size_t)B_ * T_;                        // 131072
    const size_t need = NT * 512 * 2 + NT * H_ * 4;           // 134MB + 67MB
    if (ws_size < need) {
        hipMemsetAsync(d_out, 0x7F, (size_t)out_size * 4, stream);
        return;
    }
    unsigned short* gi = (unsigned short*)d_ws;               // [m][128][4] bf16
    float* hb = (float*)(gi + NT * 512);                      // fp32 h

    const int gblocks = (int)(NT / 128);                      // 1024
    gemm_gi_mfma<<<gblocks, 512, 0, stream>>>(x, Wih0, bih0, gi);
    gru_seq<<<B_, 512, 0, stream>>>(gi, Whh0, bhh0, hb);
    gemm_gi_mfma<<<gblocks, 512, 0, stream>>>(hb, Wih1, bih1, gi);
    gru_seq<<<B_, 512, 0, stream>>>(gi, Whh1, bhh1, hb);
    head_k<<<(int)(NT / 4), 256, 0, stream>>>(hb, x, regime, W1, b1, W2, b2,
                                              lag_scale, lag_bias, out);
}